// Round 1
// 1705.281 us; speedup vs baseline: 1.2010x; 1.2010x over previous
//
#include <hip/hip_runtime.h>
#include <hip/hip_bf16.h>
#include <stdint.h>

#define NROWS 65536
#define INDIM 768
#define ODIM  256
#define NLEV  4
#define CBS   1024
#define TAUQ  2e-2f   // top-2 gap threshold for f64 re-check (split-MFMA error ~1e-3 worst, ~20x margin)

typedef __attribute__((ext_vector_type(8))) short short8;
typedef __attribute__((ext_vector_type(4))) float f32x4;

__device__ __forceinline__ float bf2f(unsigned short u) {
    union { unsigned int i; float f; } v; v.i = ((unsigned int)u) << 16; return v.f;
}
__device__ __forceinline__ unsigned short f2bf(float f) {
    union { float f; unsigned int i; } v; v.f = f;
    unsigned int r = v.i + 0x7fffu + ((v.i >> 16) & 1u);
    return (unsigned short)(r >> 16);
}
__device__ __forceinline__ f32x4 mfma_bf16(short8 a, short8 b, f32x4 c) {
    return __builtin_amdgcn_mfma_f32_16x16x32_bf16(a, b, c, 0, 0, 0);
}

// async global->LDS 16B: dest = wave-uniform base + lane*16 (HW rule)
typedef const __attribute__((address_space(1))) unsigned int GUI;
typedef __attribute__((address_space(3))) unsigned int LUI;
__device__ __forceinline__ void gld16(const void* g, void* l) {
    __builtin_amdgcn_global_load_lds((GUI*)g, (LUI*)l, 16, 0, 0);
}

__global__ void k_init(double* __restrict__ acc) {
    if (threadIdx.x < 2) acc[threadIdx.x] = 0.0;
}

// ||c||^2 per codebook row
__global__ __launch_bounds__(64) void k_cnorm(const float* __restrict__ cb, float* __restrict__ cn) {
    const int code = blockIdx.x;
    const float* r = cb + (size_t)code * ODIM + threadIdx.x * 4;
    float4 v = *(const float4*)r;
    float s = fmaf(v.x, v.x, fmaf(v.y, v.y, fmaf(v.z, v.z, v.w * v.w)));
    #pragma unroll
    for (int o = 32; o > 0; o >>= 1) s += __shfl_xor(s, o);
    if (threadIdx.x == 0) cn[code] = s;
}

// split codebooks into hi/lo bf16
__global__ __launch_bounds__(256) void k_split(const float* __restrict__ cb,
                                               unsigned short* __restrict__ ch,
                                               unsigned short* __restrict__ cl) {
    const size_t i = ((size_t)blockIdx.x * 256 + threadIdx.x) * 4;
    float4 v = *(const float4*)(cb + i);
    float e[4] = {v.x, v.y, v.z, v.w};
    ushort4 h, l;
    unsigned short* hp = &h.x; unsigned short* lp = &l.x;
    #pragma unroll
    for (int j = 0; j < 4; ++j) {
        unsigned short hh = f2bf(e[j]);
        hp[j] = hh;
        lp[j] = f2bf(e[j] - bf2f(hh));
    }
    *(ushort4*)(ch + i) = h;
    *(ushort4*)(cl + i) = l;
}

// codebook transpose for k_fix: ct[l][k][code]  (coalesced distance scan)
__global__ __launch_bounds__(256) void k_cbt(const float* __restrict__ cb, float* __restrict__ ct) {
    __shared__ float T[32][33];
    const int l  = blockIdx.z;
    const int c0 = blockIdx.x << 5;   // code tile
    const int k0 = blockIdx.y << 5;   // k tile
    const int tx = threadIdx.x & 31, ty = threadIdx.x >> 5;
    const float* src = cb + ((size_t)l * CBS + c0) * ODIM + k0;
    #pragma unroll
    for (int i = 0; i < 4; ++i)
        T[ty + (i << 3)][tx] = src[(size_t)(ty + (i << 3)) * ODIM + tx];
    __syncthreads();
    float* dst = ct + ((size_t)l * ODIM + k0) * CBS + c0;
    #pragma unroll
    for (int i = 0; i < 4; ++i)
        dst[(size_t)(ty + (i << 3)) * CBS + tx] = T[tx][ty + (i << 3)];
}

// transpose weight W[K][N] -> Th/Tl[N][K] bf16 (hi / optional lo)
__global__ __launch_bounds__(256) void k_wt(const float* __restrict__ W,
                                            unsigned short* __restrict__ Th,
                                            unsigned short* __restrict__ Tl,
                                            const int K, const int N, const int split) {
    const int n = blockIdx.x;
    for (int k = threadIdx.x; k < K; k += 256) {
        float v = W[(size_t)k * N + n];
        unsigned short h = f2bf(v);
        Th[(size_t)n * K + k] = h;
        if (split) Tl[(size_t)n * K + k] = f2bf(v - bf2f(h));
    }
}

// per-row mean / rsqrt(var+eps)
__global__ __launch_bounds__(256) void k_ln(const float* __restrict__ x,
                                            float* __restrict__ mu, float* __restrict__ rsig) {
    const int row = blockIdx.x;
    const int t = threadIdx.x;
    const float* xr = x + (size_t)row * INDIM;
    float a = xr[t], b = xr[t + 256], c = xr[t + 512];
    float s1 = a + b + c;
    float s2 = fmaf(a, a, fmaf(b, b, c * c));
    #pragma unroll
    for (int o = 32; o > 0; o >>= 1) { s1 += __shfl_xor(s1, o); s2 += __shfl_xor(s2, o); }
    __shared__ float r1[4], r2[4];
    if ((t & 63) == 0) { r1[t >> 6] = s1; r2[t >> 6] = s2; }
    __syncthreads();
    if (t == 0) {
        float S1 = (r1[0] + r1[1]) + (r1[2] + r1[3]);
        float S2 = (r2[0] + r2[1]) + (r2[2] + r2[3]);
        float m = S1 * (1.0f / INDIM);
        float var = S2 * (1.0f / INDIM) - m * m;
        mu[row] = m;
        rsig[row] = rsqrtf(var + 1e-5f);
    }
}

// MFMA GEMM: C[M,Nc] = op(A[M,K]) @ Bt^T + bias, Bt pre-transposed [Nc][K] bf16.
// Block: 128(M) x 256(N), 4 waves in 2x2; wave tile 64m x 128n = 4mt x 8nt (acc 128 f32/lane).
// AMODE: 0 f32 A (split hi/lo), 1 LayerNorm-on-load f32 A (split), 2 bf16 A (plain)
// SPLIT: 1 = bf16x2-split (3 MFMAs: hh + lh + hl), 0 = plain bf16
// EPI:   0 relu->f32, 1 f32, 2 relu->bf16, 3 f32 + sum((C-xref)^2) into acc_rec
template <int AMODE, int SPLIT, int EPI>
__global__ __launch_bounds__(256, 2) void k_gemm_mfma(
    const void* __restrict__ Ap, const unsigned short* __restrict__ Bh,
    const unsigned short* __restrict__ Bl,
    const float* __restrict__ bias, void* __restrict__ Cp,
    const int K, const int Nc,
    const float* __restrict__ mu, const float* __restrict__ rsig,
    const float* __restrict__ lng, const float* __restrict__ lnb,
    const float* __restrict__ xref, double* __restrict__ acc_rec)
{
    __shared__ __align__(16) unsigned short BhS[256][40];             // [n][k] pad 8
    __shared__ __align__(16) unsigned short BlS[SPLIT ? 256 : 8][SPLIT ? 40 : 8];
    __shared__ float credsh[4];

    const int t = threadIdx.x;
    const int wave = t >> 6, lane = t & 63;
    const int lg = lane >> 4, lm = lane & 15;
    const int wm = wave >> 1, wn = wave & 1;
    const size_t rowb = (size_t)blockIdx.y * 128 + wm * 64;
    const int nb = blockIdx.x << 8;

    f32x4 acc[4][8];
    #pragma unroll
    for (int mt = 0; mt < 4; ++mt)
        #pragma unroll
        for (int nt = 0; nt < 8; ++nt) acc[mt][nt] = (f32x4){0.f, 0.f, 0.f, 0.f};

    float lnm[4], lnr[4];
    if (AMODE == 1) {
        #pragma unroll
        for (int mt = 0; mt < 4; ++mt) {
            lnm[mt] = mu[rowb + (mt << 4) + lm];
            lnr[mt] = rsig[rowb + (mt << 4) + lm];
        }
    }

    for (int kk = 0; kk < K; kk += 32) {
        // ---- A fragments: per-lane direct global loads ----
        short8 Ah[4], Al[4];
        if (AMODE == 2) {
            #pragma unroll
            for (int mt = 0; mt < 4; ++mt)
                Ah[mt] = *(const short8*)((const unsigned short*)Ap +
                          (rowb + (mt << 4) + lm) * (size_t)K + kk + (lg << 3));
        } else {
            float g[8], bb[8];
            if (AMODE == 1) {
                float4 g0 = *(const float4*)(lng + kk + (lg << 3));
                float4 g1 = *(const float4*)(lng + kk + (lg << 3) + 4);
                float4 b0 = *(const float4*)(lnb + kk + (lg << 3));
                float4 b1 = *(const float4*)(lnb + kk + (lg << 3) + 4);
                g[0]=g0.x; g[1]=g0.y; g[2]=g0.z; g[3]=g0.w; g[4]=g1.x; g[5]=g1.y; g[6]=g1.z; g[7]=g1.w;
                bb[0]=b0.x; bb[1]=b0.y; bb[2]=b0.z; bb[3]=b0.w; bb[4]=b1.x; bb[5]=b1.y; bb[6]=b1.z; bb[7]=b1.w;
            }
            #pragma unroll
            for (int mt = 0; mt < 4; ++mt) {
                const float* ar = (const float*)Ap + (rowb + (mt << 4) + lm) * (size_t)K + kk + (lg << 3);
                float4 a0 = *(const float4*)ar;
                float4 a1 = *(const float4*)(ar + 4);
                float e[8] = {a0.x, a0.y, a0.z, a0.w, a1.x, a1.y, a1.z, a1.w};
                #pragma unroll
                for (int j = 0; j < 8; ++j) {
                    float v = e[j];
                    if (AMODE == 1) v = fmaf((v - lnm[mt]) * lnr[mt], g[j], bb[j]);
                    unsigned short h = f2bf(v);
                    Ah[mt][j] = (short)h;
                    Al[mt][j] = (short)f2bf(v - bf2f(h));
                }
            }
        }
        // ---- stage B tile [256 n][32 k] ----
        __syncthreads();
        {
            const unsigned short* gh = Bh + (size_t)nb * K + kk;
            #pragma unroll
            for (int it = 0; it < 4; ++it) {
                const int idx = (it << 8) + t;
                const int n = idx >> 2, sl = idx & 3;
                *(uint4*)&BhS[n][sl << 3] = *(const uint4*)(gh + (size_t)n * K + (sl << 3));
            }
            if (SPLIT) {
                const unsigned short* gl = Bl + (size_t)nb * K + kk;
                #pragma unroll
                for (int it = 0; it < 4; ++it) {
                    const int idx = (it << 8) + t;
                    const int n = idx >> 2, sl = idx & 3;
                    *(uint4*)&BlS[n][sl << 3] = *(const uint4*)(gl + (size_t)n * K + (sl << 3));
                }
            }
        }
        __syncthreads();
        // ---- MFMA: 4mt x 8nt ----
        #pragma unroll
        for (int nt = 0; nt < 8; ++nt) {
            const int nl = (wn << 7) + (nt << 4) + lm;
            short8 bh = *(const short8*)&BhS[nl][lg << 3];
            if (!SPLIT) {
                #pragma unroll
                for (int mt = 0; mt < 4; ++mt)
                    acc[mt][nt] = mfma_bf16(Ah[mt], bh, acc[mt][nt]);
            } else {
                short8 bl = *(const short8*)&BlS[nl][lg << 3];
                #pragma unroll
                for (int mt = 0; mt < 4; ++mt) {
                    acc[mt][nt] = mfma_bf16(Ah[mt], bh, acc[mt][nt]);
                    acc[mt][nt] = mfma_bf16(Al[mt], bh, acc[mt][nt]);
                    acc[mt][nt] = mfma_bf16(Ah[mt], bl, acc[mt][nt]);
                }
            }
        }
    }

    // ---- epilogue: C[row = rowb+mt*16+lg*4+r][col = nb+wn*128+nt*16+lm] ----
    float lsum = 0.0f;
    #pragma unroll
    for (int nt = 0; nt < 8; ++nt) {
        const int col = nb + (wn << 7) + (nt << 4) + lm;
        const float bs = bias[col];
        #pragma unroll
        for (int mt = 0; mt < 4; ++mt) {
            #pragma unroll
            for (int r = 0; r < 4; ++r) {
                float v = acc[mt][nt][r] + bs;
                if (EPI == 0 || EPI == 2) v = fmaxf(v, 0.0f);
                const size_t row = rowb + (mt << 4) + (lg << 2) + r;
                if (EPI == 2) {
                    ((unsigned short*)Cp)[row * Nc + col] = f2bf(v);
                } else {
                    ((float*)Cp)[row * Nc + col] = v;
                }
                if (EPI == 3) {
                    const float d = v - xref[row * Nc + col];
                    lsum = fmaf(d, d, lsum);
                }
            }
        }
    }
    if (EPI == 3) {
        #pragma unroll
        for (int o = 32; o > 0; o >>= 1) lsum += __shfl_xor(lsum, o);
        if (lane == 0) credsh[wave] = lsum;
        __syncthreads();
        if (t == 0) atomicAdd(acc_rec, (double)((credsh[0] + credsh[1]) + (credsh[2] + credsh[3])));
    }
}

// Fused 4-level residual quantization, MFMA bf16x2-split edition.
// Block = 256 thr = 4 waves; wave owns 32 rows (2 MFMA m-tiles) held entirely in
// registers as hi/lo bf16 A-fragments. Codebook hi/lo async-double-buffer-streamed
// through LDS (global_load_lds, pre-swizzled source + XOR-swizzled reads) in
// 32-code chunks; ONE barrier per chunk, prefetch hides L2/L3 latency under MFMA.
// dist = ||c||^2 - 2*(r_hi.c_hi + r_lo.c_hi + r_hi.c_lo).
__global__ __launch_bounds__(256, 2) void k_quant_mfma(
    const float* __restrict__ enc, const float* __restrict__ cb,
    const unsigned short* __restrict__ cbh, const unsigned short* __restrict__ cbl,
    const float* __restrict__ cnorm, unsigned short* __restrict__ qf, float* __restrict__ oidx,
    int* __restrict__ flag, double* __restrict__ acc_commit)
{
    // linear [32][256]-short chunk images, double buffered; value at semantic
    // (row, colbyte c) lives at byte row*512 + (c ^ ((row&7)<<4)).
    __shared__ __align__(128) unsigned short Bh[2][32][256];
    __shared__ __align__(128) unsigned short Bl[2][32][256];
    __shared__ __align__(16) int rowidxsh[128];
    __shared__ float credsh[4];

    const int t = threadIdx.x;
    const int wave = t >> 6, lane = t & 63;
    const int lg = lane >> 4, lm = lane & 15;
    const size_t rowbase = (size_t)blockIdx.x * 128 + wave * 32;

// stage one 32-code chunk (16KB hi + 16KB lo) into buffer b_ via async gload_lds;
// source address pre-swizzled so that swizzled READS return linear data (rule #21).
#define STAGE_CHUNK(b_, gh_, gl_) do {                                          \
    _Pragma("unroll")                                                           \
    for (int i_ = 0; i_ < 4; ++i_) {                                            \
        const int seg_ = (i_ << 2) + wave;                                      \
        const int off_ = (seg_ << 10) + (lane << 4);                            \
        const int src_ = off_ ^ (((off_ >> 9) & 7) << 4);                       \
        gld16((const char*)(gh_) + src_, (char*)&Bh[b_][0][0] + (seg_ << 10));  \
        gld16((const char*)(gl_) + src_, (char*)&Bl[b_][0][0] + (seg_ << 10));  \
    }                                                                           \
} while (0)

    // prologue: prefetch (level 0, chunk 0) into buffer 0 (overlaps A-frag build)
    STAGE_CHUNK(0, cbh, cbl);
    int buf = 0;

    // ---- load enc rows into hi/lo A-fragments (A[m=lane&15][k=lg*8+j], 8 k-steps) ----
    short8 Ah[2][8], Al[2][8];
    #pragma unroll
    for (int mt = 0; mt < 2; ++mt)
        #pragma unroll
        for (int s = 0; s < 8; ++s) {
            const float* er = enc + (rowbase + mt * 16 + lm) * ODIM + s * 32 + lg * 8;
            float4 e0 = *(const float4*)er;
            float4 e1 = *(const float4*)(er + 4);
            float e[8] = {e0.x, e0.y, e0.z, e0.w, e1.x, e1.y, e1.z, e1.w};
            #pragma unroll
            for (int j = 0; j < 8; ++j) {
                unsigned short h = f2bf(e[j]);
                Ah[mt][s][j] = (short)h;
                Al[mt][s][j] = (short)f2bf(e[j] - bf2f(h));
            }
        }

    float commit_local = 0.0f;
    int flg[2][4] = {{0, 0, 0, 0}, {0, 0, 0, 0}};

    for (int l = 0; l < NLEV; ++l) {
        float bestv[2][4], b2v[2][4];
        int besti[2][4];
        #pragma unroll
        for (int mt = 0; mt < 2; ++mt)
            #pragma unroll
            for (int r = 0; r < 4; ++r) { bestv[mt][r] = 3.4e38f; b2v[mt][r] = 3.4e38f; besti[mt][r] = 0; }

        for (int ch = 0; ch < 32; ++ch) {
            // buffer `buf` holds (l,ch) after this barrier (drains prefetch vmcnt);
            // it also guarantees all waves are done reading buf^1 before we refill it.
            __syncthreads();
            {
                const int cc = (l << 5) + ch + 1;          // next chunk, flattened
                if (cc < 128) {
                    const unsigned short* gh = cbh + ((size_t)(cc >> 5) << 18) + ((size_t)(cc & 31) << 13);
                    const unsigned short* gl = cbl + ((size_t)(cc >> 5) << 18) + ((size_t)(cc & 31) << 13);
                    STAGE_CHUNK(buf ^ 1, gh, gl);
                }
            }
            const int cbase = ch << 5;
            const unsigned short* bbh = &Bh[buf][0][0];
            const unsigned short* bbl = &Bl[buf][0][0];
            #pragma unroll
            for (int nt = 0; nt < 2; ++nt) {
                const int rowB = (nt << 4) + lm;
                const int rbase = rowB << 9;               // row byte base
                const int xm = (rowB & 7) << 4;            // XOR swizzle mask
                f32x4 hh[2], lh[2], hl[2];
                #pragma unroll
                for (int mt = 0; mt < 2; ++mt) {
                    hh[mt] = (f32x4){0.f, 0.f, 0.f, 0.f};
                    lh[mt] = (f32x4){0.f, 0.f, 0.f, 0.f};
                    hl[mt] = (f32x4){0.f, 0.f, 0.f, 0.f};
                }
                #pragma unroll
                for (int s = 0; s < 8; ++s) {
                    const int a = rbase + (((s << 6) + (lg << 4)) ^ xm);
                    short8 bh = *(const short8*)((const char*)bbh + a);
                    short8 bl = *(const short8*)((const char*)bbl + a);
                    hh[0] = mfma_bf16(Ah[0][s], bh, hh[0]);
                    hh[1] = mfma_bf16(Ah[1][s], bh, hh[1]);
                    lh[0] = mfma_bf16(Al[0][s], bh, lh[0]);
                    lh[1] = mfma_bf16(Al[1][s], bh, lh[1]);
                    hl[0] = mfma_bf16(Ah[0][s], bl, hl[0]);
                    hl[1] = mfma_bf16(Ah[1][s], bl, hl[1]);
                }
                const int code = cbase + (nt << 4) + lm;
                const float cn = cnorm[(l << 10) + code];
                #pragma unroll
                for (int mt = 0; mt < 2; ++mt)
                    #pragma unroll
                    for (int r = 0; r < 4; ++r) {
                        const float dot = hh[mt][r] + lh[mt][r] + hl[mt][r];
                        const float d = fmaf(-2.0f, dot, cn);
                        if (d < bestv[mt][r]) {
                            b2v[mt][r] = bestv[mt][r]; bestv[mt][r] = d; besti[mt][r] = code;
                        } else {
                            b2v[mt][r] = fminf(b2v[mt][r], d);
                        }
                    }
            }
            buf ^= 1;
        }

        // ---- cross-lane argmin over the 16 C-columns (xor butterfly in low 4 lane bits) ----
        #pragma unroll
        for (int mt = 0; mt < 2; ++mt) {
            int iv[4];
            #pragma unroll
            for (int r = 0; r < 4; ++r) {
                float bv = bestv[mt][r], b2 = b2v[mt][r];
                int bi = besti[mt][r];
                #pragma unroll
                for (int off = 1; off < 16; off <<= 1) {
                    float ov = __shfl_xor(bv, off);
                    float o2 = __shfl_xor(b2, off);
                    int   oi = __shfl_xor(bi, off);
                    if (ov < bv)      { b2 = fminf(bv, o2); bv = ov; bi = oi; }
                    else if (ov > bv) { b2 = fminf(b2, ov); }
                    else              { b2 = bv; bi = (oi < bi) ? oi : bi; }
                }
                flg[mt][r] |= (b2 - bv < TAUQ) ? 1 : 0;
                iv[r] = bi;
                if (lm == 0)
                    oidx[(rowbase + (mt << 4) + (lg << 2) + r) * NLEV + l] = (float)bi;
            }
            if (lm == 0)
                *(int4*)&rowidxsh[(wave << 5) + (mt << 4) + (lg << 2)] = make_int4(iv[0], iv[1], iv[2], iv[3]);
        }
        __syncthreads();

        // ---- residual update in registers: r -= cb[best]; commit += r^2; re-split ----
        const size_t lbase = (size_t)l * CBS * ODIM;
        #pragma unroll
        for (int mt = 0; mt < 2; ++mt) {
            const int ci = rowidxsh[(wave << 5) + (mt << 4) + lm];
            const float* cr = cb + lbase + (size_t)ci * ODIM + lg * 8;
            #pragma unroll
            for (int s = 0; s < 8; ++s) {
                float4 c0 = *(const float4*)(cr + (s << 5));
                float4 c1 = *(const float4*)(cr + (s << 5) + 4);
                float c[8] = {c0.x, c0.y, c0.z, c0.w, c1.x, c1.y, c1.z, c1.w};
                #pragma unroll
                for (int j = 0; j < 8; ++j) {
                    float rr = bf2f((unsigned short)Ah[mt][s][j]) + bf2f((unsigned short)Al[mt][s][j]) - c[j];
                    commit_local = fmaf(rr, rr, commit_local);
                    unsigned short h = f2bf(rr);
                    Ah[mt][s][j] = (short)h;
                    Al[mt][s][j] = (short)f2bf(rr - bf2f(h));
                }
            }
        }
    }
#undef STAGE_CHUNK

    // ---- q_final = enc - r_final, stored bf16 for the MFMA decoder ----
    #pragma unroll
    for (int mt = 0; mt < 2; ++mt)
        #pragma unroll
        for (int s = 0; s < 8; ++s) {
            const size_t ro = (rowbase + mt * 16 + lm) * ODIM + s * 32 + lg * 8;
            float4 e0 = *(const float4*)(enc + ro);
            float4 e1 = *(const float4*)(enc + ro + 4);
            float e[8] = {e0.x, e0.y, e0.z, e0.w, e1.x, e1.y, e1.z, e1.w};
            unsigned short q[8];
            #pragma unroll
            for (int j = 0; j < 8; ++j)
                q[j] = f2bf(e[j] - (bf2f((unsigned short)Ah[mt][s][j]) + bf2f((unsigned short)Al[mt][s][j])));
            *(ushort4*)(qf + ro)     = make_ushort4(q[0], q[1], q[2], q[3]);
            *(ushort4*)(qf + ro + 4) = make_ushort4(q[4], q[5], q[6], q[7]);
        }

    if (lm == 0) {
        #pragma unroll
        for (int mt = 0; mt < 2; ++mt)
            #pragma unroll
            for (int r = 0; r < 4; ++r)
                flag[rowbase + (mt << 4) + (lg << 2) + r] = flg[mt][r];
    }

    #pragma unroll
    for (int o = 32; o > 0; o >>= 1) commit_local += __shfl_xor(commit_local, o);
    if (lane == 0) credsh[wave] = commit_local;
    __syncthreads();
    if (t == 0) atomicAdd(acc_commit, (double)((credsh[0] + credsh[1]) + (credsh[2] + credsh[3])));
}

// f64 exact recompute of the index chain for flagged (near-tie) rows.
// Distance scan reads the TRANSPOSED codebook ct[l][k][code]: one coalesced
// float4 per k per lane (codes 4t..4t+3) instead of the stride-1KB 16B walk.
__global__ __launch_bounds__(256) void k_fix(
    const int* __restrict__ flag, const float* __restrict__ x,
    const float* __restrict__ lng, const float* __restrict__ lnb,
    const float* __restrict__ W1, const float* __restrict__ b1,
    const float* __restrict__ W2, const float* __restrict__ b2,
    const float* __restrict__ cb, const float* __restrict__ ct,
    float* __restrict__ oidx)
{
    const int row = blockIdx.x;
    if (!flag[row]) return;
    const int t = threadIdx.x;
    __shared__ double xn[INDIM];
    __shared__ double hs[ODIM];
    __shared__ double r[ODIM];
    __shared__ double rv_[4];
    __shared__ int ri_[4];
    __shared__ int selidx;

    const float* xr = x + (size_t)row * INDIM;
    double xa = (double)xr[t], xb = (double)xr[t + 256], xc = (double)xr[t + 512];
    double s1 = xa + xb + xc;
    double s2 = xa * xa + xb * xb + xc * xc;
    #pragma unroll
    for (int o = 32; o > 0; o >>= 1) { s1 += __shfl_xor(s1, o); s2 += __shfl_xor(s2, o); }
    __shared__ double w1r[4], w2r[4];
    if ((t & 63) == 0) { w1r[t >> 6] = s1; w2r[t >> 6] = s2; }
    __syncthreads();
    double S1 = (w1r[0] + w1r[1]) + (w1r[2] + w1r[3]);
    double S2 = (w2r[0] + w2r[1]) + (w2r[2] + w2r[3]);
    double mu = S1 / (double)INDIM;
    double var = S2 / (double)INDIM - mu * mu;
    double rs = 1.0 / sqrt(var + 1e-5);
    xn[t]       = (xa - mu) * rs * (double)lng[t]       + (double)lnb[t];
    xn[t + 256] = (xb - mu) * rs * (double)lng[t + 256] + (double)lnb[t + 256];
    xn[t + 512] = (xc - mu) * rs * (double)lng[t + 512] + (double)lnb[t + 512];
    __syncthreads();
    {
        double a0 = 0.0, a1 = 0.0, a2 = 0.0, a3 = 0.0;
        for (int k = 0; k < INDIM; k += 4) {
            a0 = fma(xn[k + 0], (double)W1[(size_t)(k + 0) * ODIM + t], a0);
            a1 = fma(xn[k + 1], (double)W1[(size_t)(k + 1) * ODIM + t], a1);
            a2 = fma(xn[k + 2], (double)W1[(size_t)(k + 2) * ODIM + t], a2);
            a3 = fma(xn[k + 3], (double)W1[(size_t)(k + 3) * ODIM + t], a3);
        }
        hs[t] = fmax(((a0 + a1) + (a2 + a3)) + (double)b1[t], 0.0);
    }
    __syncthreads();
    {
        double a0 = 0.0, a1 = 0.0, a2 = 0.0, a3 = 0.0;
        for (int k = 0; k < ODIM; k += 4) {
            a0 = fma(hs[k + 0], (double)W2[(size_t)(k + 0) * ODIM + t], a0);
            a1 = fma(hs[k + 1], (double)W2[(size_t)(k + 1) * ODIM + t], a1);
            a2 = fma(hs[k + 2], (double)W2[(size_t)(k + 2) * ODIM + t], a2);
            a3 = fma(hs[k + 3], (double)W2[(size_t)(k + 3) * ODIM + t], a3);
        }
        r[t] = ((a0 + a1) + (a2 + a3)) + (double)b2[t];
    }
    __syncthreads();

    for (int l = 0; l < NLEV; ++l) {
        const float* ctl = ct + (size_t)l * CBS * ODIM;   // [k][code]
        double d0 = 0.0, d1 = 0.0, d2 = 0.0, d3 = 0.0;
        #pragma unroll 4
        for (int k = 0; k < ODIM; ++k) {
            const double rk = r[k];
            const float4 c4 = *(const float4*)(ctl + ((size_t)k << 10) + (t << 2));
            const double f0 = rk - (double)c4.x;
            const double f1 = rk - (double)c4.y;
            const double f2 = rk - (double)c4.z;
            const double f3 = rk - (double)c4.w;
            d0 = fma(f0, f0, d0); d1 = fma(f1, f1, d1);
            d2 = fma(f2, f2, d2); d3 = fma(f3, f3, d3);
        }
        // per-thread best over codes {4t, 4t+1, 4t+2, 4t+3} (ascending -> lowest-index tie-break)
        double bv = d0; int bi = (t << 2);
        if (d1 < bv) { bv = d1; bi = (t << 2) + 1; }
        if (d2 < bv) { bv = d2; bi = (t << 2) + 2; }
        if (d3 < bv) { bv = d3; bi = (t << 2) + 3; }
        #pragma unroll
        for (int o = 32; o > 0; o >>= 1) {
            double ov = __shfl_xor(bv, o);
            int oi = __shfl_xor(bi, o);
            if (ov < bv || (ov == bv && oi < bi)) { bv = ov; bi = oi; }
        }
        if ((t & 63) == 0) { rv_[t >> 6] = bv; ri_[t >> 6] = bi; }
        __syncthreads();
        if (t == 0) {
            double fv = rv_[0]; int fi = ri_[0];
            #pragma unroll
            for (int w = 1; w < 4; ++w)
                if (rv_[w] < fv || (rv_[w] == fv && ri_[w] < fi)) { fv = rv_[w]; fi = ri_[w]; }
            selidx = fi;
            oidx[(size_t)row * NLEV + l] = (float)fi;
        }
        __syncthreads();
        r[t] = r[t] - (double)cb[(size_t)l * CBS * ODIM + (size_t)selidx * ODIM + t];
        __syncthreads();
    }
}

__global__ void k_fin(const double* __restrict__ acc, float* __restrict__ out) {
    if (threadIdx.x == 0)
        out[0] = (float)(acc[1] / ((double)NROWS * (double)INDIM) +
                         0.25 * (acc[0] / ((double)NROWS * (double)ODIM)));
}

extern "C" void kernel_launch(void* const* d_in, const int* in_sizes, int n_in,
                              void* d_out, int out_size, void* d_ws, size_t ws_size,
                              hipStream_t stream)
{
    const float* x   = (const float*)d_in[0];
    const float* lng = (const float*)d_in[1];
    const float* lnb = (const float*)d_in[2];
    const float* W1  = (const float*)d_in[3];
    const float* b1  = (const float*)d_in[4];
    const float* W2  = (const float*)d_in[5];
    const float* b2  = (const float*)d_in[6];
    const float* Wd1 = (const float*)d_in[7];
    const float* bd1 = (const float*)d_in[8];
    const float* Wd2 = (const float*)d_in[9];
    const float* bd2 = (const float*)d_in[10];
    const float* cbs = (const float*)d_in[11];

    char* ws = (char*)d_ws;
    const size_t MB = 1u << 20;
    const size_t O_ACC  = 0;
    const size_t O_CN   = 1024;
    const size_t O_MU   = O_CN + 16384;
    const size_t O_RS   = O_MU + (size_t)NROWS * 4;
    const size_t O_FLAG = O_RS + (size_t)NROWS * 4;
    const size_t O_ENC  = 1 * MB;                 // 64 MB f32
    const size_t O_QF   = 65 * MB;                // 32 MB bf16
    const size_t O_W1H  = 97 * MB;                // transposed weights, ~2.5 MB total
    const size_t O_W1L  = O_W1H + (size_t)INDIM * ODIM * 2;
    const size_t O_W2H  = O_W1L + (size_t)INDIM * ODIM * 2;
    const size_t O_W2L  = O_W2H + (size_t)ODIM * ODIM * 2;
    const size_t O_WD1  = O_W2L + (size_t)ODIM * ODIM * 2;
    const size_t O_WD2  = O_WD1 + (size_t)ODIM * INDIM * 2;
    const size_t O_CBH  = 100 * MB;               // 2 MB
    const size_t O_CBL  = 102 * MB;               // 2 MB
    const size_t O_H1   = 104 * MB;               // h1 f32 64 MB, later aliased by hd bf16 100 MB
    const size_t O_CT   = O_H1;                   // ct f32 4 MB aliases h1 (free after GEMM2, before decoder)

    double* acc   = (double*)(ws + O_ACC);   // [0]=commit sum, [1]=rec sum
    float* cnorm  = (float*)(ws + O_CN);
    float* mu     = (float*)(ws + O_MU);
    float* rsig   = (float*)(ws + O_RS);
    int*   flag   = (int*)(ws + O_FLAG);
    float* enc    = (float*)(ws + O_ENC);
    unsigned short* qf  = (unsigned short*)(ws + O_QF);
    unsigned short* w1h = (unsigned short*)(ws + O_W1H);
    unsigned short* w1l = (unsigned short*)(ws + O_W1L);
    unsigned short* w2h = (unsigned short*)(ws + O_W2H);
    unsigned short* w2l = (unsigned short*)(ws + O_W2L);
    unsigned short* wd1h = (unsigned short*)(ws + O_WD1);
    unsigned short* wd2h = (unsigned short*)(ws + O_WD2);
    unsigned short* cbh = (unsigned short*)(ws + O_CBH);
    unsigned short* cbl = (unsigned short*)(ws + O_CBL);
    float* h1     = (float*)(ws + O_H1);
    float* ct     = (float*)(ws + O_CT);
    unsigned short* hd = (unsigned short*)(ws + O_H1);

    float* outF  = (float*)d_out;
    float* recon = outF + 1;
    float* oidx  = outF + 1 + (size_t)NROWS * INDIM;

    k_init<<<1, 64, 0, stream>>>(acc);
    k_cnorm<<<NLEV * CBS, 64, 0, stream>>>(cbs, cnorm);
    k_ln<<<NROWS, 256, 0, stream>>>(x, mu, rsig);
    // weight transpose + bf16(x2) conversion
    k_wt<<<ODIM, 256, 0, stream>>>(W1, w1h, w1l, INDIM, ODIM, 1);
    k_wt<<<ODIM, 256, 0, stream>>>(W2, w2h, w2l, ODIM, ODIM, 1);
    k_wt<<<INDIM, 256, 0, stream>>>(Wd1, wd1h, nullptr, ODIM, INDIM, 0);
    k_wt<<<INDIM, 256, 0, stream>>>(Wd2, wd2h, nullptr, INDIM, INDIM, 0);
    k_split<<<(NLEV * CBS * ODIM) / 1024, 256, 0, stream>>>(cbs, cbh, cbl);
    // encoder: LN(x)@W1 relu -> h1;  h1@W2 -> enc   (bf16x2-split MFMA)
    k_gemm_mfma<1, 1, 0><<<dim3(1, NROWS / 128), 256, 0, stream>>>(
        x, w1h, w1l, b1, h1, INDIM, ODIM, mu, rsig, lng, lnb, nullptr, nullptr);
    k_gemm_mfma<0, 1, 1><<<dim3(1, NROWS / 128), 256, 0, stream>>>(
        h1, w2h, w2l, b2, enc, ODIM, ODIM, nullptr, nullptr, nullptr, nullptr, nullptr, nullptr);
    // codebook transpose for k_fix (h1 is dead from here on; hd overwrites ct only after k_fix)
    k_cbt<<<dim3(32, 8, 4), 256, 0, stream>>>(cbs, ct);
    // residual quantization: MFMA bf16x2-split + near-tie flags, qf out bf16
    k_quant_mfma<<<NROWS / 128, 256, 0, stream>>>(enc, cbs, cbh, cbl, cnorm, qf, oidx, flag, acc);
    // f64 exact index fix for flagged rows (coalesced transposed-codebook scan)
    k_fix<<<NROWS, 256, 0, stream>>>(flag, x, lng, lnb, W1, b1, W2, b2, cbs, ct, oidx);
    // decoder: qf@Wd1 relu -> hd (bf16);  hd@Wd2 -> recon + rec_loss   (plain bf16 MFMA)
    k_gemm_mfma<2, 0, 2><<<dim3(INDIM / 256, NROWS / 128), 256, 0, stream>>>(
        qf, wd1h, nullptr, bd1, hd, ODIM, INDIM, nullptr, nullptr, nullptr, nullptr, nullptr, nullptr);
    k_gemm_mfma<2, 0, 3><<<dim3(INDIM / 256, NROWS / 128), 256, 0, stream>>>(
        hd, wd2h, nullptr, bd2, recon, INDIM, INDIM, nullptr, nullptr, nullptr, nullptr, x, acc + 1);
    k_fin<<<1, 64, 0, stream>>>(acc, outF);
}

// Round 2
// 1626.217 us; speedup vs baseline: 1.2594x; 1.0486x over previous
//
#include <hip/hip_runtime.h>
#include <hip/hip_bf16.h>
#include <stdint.h>

#define NROWS 65536
#define INDIM 768
#define ODIM  256
#define NLEV  4
#define CBS   1024
#define TAUQ  2e-2f   // top-2 gap threshold for f64 re-check (split-MFMA error ~1e-3 worst, ~20x margin)

typedef __attribute__((ext_vector_type(8))) short short8;
typedef __attribute__((ext_vector_type(4))) float f32x4;

__device__ __forceinline__ float bf2f(unsigned short u) {
    union { unsigned int i; float f; } v; v.i = ((unsigned int)u) << 16; return v.f;
}
__device__ __forceinline__ unsigned short f2bf(float f) {
    union { float f; unsigned int i; } v; v.f = f;
    unsigned int r = v.i + 0x7fffu + ((v.i >> 16) & 1u);
    return (unsigned short)(r >> 16);
}
__device__ __forceinline__ f32x4 mfma_bf16(short8 a, short8 b, f32x4 c) {
    return __builtin_amdgcn_mfma_f32_16x16x32_bf16(a, b, c, 0, 0, 0);
}

// async global->LDS 16B: dest = wave-uniform base + lane*16 (HW rule)
typedef const __attribute__((address_space(1))) unsigned int GUI;
typedef __attribute__((address_space(3))) unsigned int LUI;
__device__ __forceinline__ void gld16(const void* g, void* l) {
    __builtin_amdgcn_global_load_lds((GUI*)g, (LUI*)l, 16, 0, 0);
}

__global__ void k_init(double* __restrict__ acc) {
    if (threadIdx.x < 2) acc[threadIdx.x] = 0.0;
}

// ||c||^2 per codebook row
__global__ __launch_bounds__(64) void k_cnorm(const float* __restrict__ cb, float* __restrict__ cn) {
    const int code = blockIdx.x;
    const float* r = cb + (size_t)code * ODIM + threadIdx.x * 4;
    float4 v = *(const float4*)r;
    float s = fmaf(v.x, v.x, fmaf(v.y, v.y, fmaf(v.z, v.z, v.w * v.w)));
    #pragma unroll
    for (int o = 32; o > 0; o >>= 1) s += __shfl_xor(s, o);
    if (threadIdx.x == 0) cn[code] = s;
}

// split codebooks into hi/lo bf16
__global__ __launch_bounds__(256) void k_split(const float* __restrict__ cb,
                                               unsigned short* __restrict__ ch,
                                               unsigned short* __restrict__ cl) {
    const size_t i = ((size_t)blockIdx.x * 256 + threadIdx.x) * 4;
    float4 v = *(const float4*)(cb + i);
    float e[4] = {v.x, v.y, v.z, v.w};
    ushort4 h, l;
    unsigned short* hp = &h.x; unsigned short* lp = &l.x;
    #pragma unroll
    for (int j = 0; j < 4; ++j) {
        unsigned short hh = f2bf(e[j]);
        hp[j] = hh;
        lp[j] = f2bf(e[j] - bf2f(hh));
    }
    *(ushort4*)(ch + i) = h;
    *(ushort4*)(cl + i) = l;
}

// codebook transpose for k_fix: ct[l][k][code]  (coalesced distance scan)
__global__ __launch_bounds__(256) void k_cbt(const float* __restrict__ cb, float* __restrict__ ct) {
    __shared__ float T[32][33];
    const int l  = blockIdx.z;
    const int c0 = blockIdx.x << 5;   // code tile
    const int k0 = blockIdx.y << 5;   // k tile
    const int tx = threadIdx.x & 31, ty = threadIdx.x >> 5;
    const float* src = cb + ((size_t)l * CBS + c0) * ODIM + k0;
    #pragma unroll
    for (int i = 0; i < 4; ++i)
        T[ty + (i << 3)][tx] = src[(size_t)(ty + (i << 3)) * ODIM + tx];
    __syncthreads();
    float* dst = ct + ((size_t)l * ODIM + k0) * CBS + c0;
    #pragma unroll
    for (int i = 0; i < 4; ++i)
        dst[(size_t)(ty + (i << 3)) * CBS + tx] = T[tx][ty + (i << 3)];
}

// transpose weight W[K][N] -> Th/Tl[N][K] bf16 (hi / optional lo)
__global__ __launch_bounds__(256) void k_wt(const float* __restrict__ W,
                                            unsigned short* __restrict__ Th,
                                            unsigned short* __restrict__ Tl,
                                            const int K, const int N, const int split) {
    const int n = blockIdx.x;
    for (int k = threadIdx.x; k < K; k += 256) {
        float v = W[(size_t)k * N + n];
        unsigned short h = f2bf(v);
        Th[(size_t)n * K + k] = h;
        if (split) Tl[(size_t)n * K + k] = f2bf(v - bf2f(h));
    }
}

// per-row mean / rsqrt(var+eps)
__global__ __launch_bounds__(256) void k_ln(const float* __restrict__ x,
                                            float* __restrict__ mu, float* __restrict__ rsig) {
    const int row = blockIdx.x;
    const int t = threadIdx.x;
    const float* xr = x + (size_t)row * INDIM;
    float a = xr[t], b = xr[t + 256], c = xr[t + 512];
    float s1 = a + b + c;
    float s2 = fmaf(a, a, fmaf(b, b, c * c));
    #pragma unroll
    for (int o = 32; o > 0; o >>= 1) { s1 += __shfl_xor(s1, o); s2 += __shfl_xor(s2, o); }
    __shared__ float r1[4], r2[4];
    if ((t & 63) == 0) { r1[t >> 6] = s1; r2[t >> 6] = s2; }
    __syncthreads();
    if (t == 0) {
        float S1 = (r1[0] + r1[1]) + (r1[2] + r1[3]);
        float S2 = (r2[0] + r2[1]) + (r2[2] + r2[3]);
        float m = S1 * (1.0f / INDIM);
        float var = S2 * (1.0f / INDIM) - m * m;
        mu[row] = m;
        rsig[row] = rsqrtf(var + 1e-5f);
    }
}

// MFMA GEMM: C[M,Nc] = op(A[M,K]) @ Bt^T + bias, Bt pre-transposed [Nc][K] bf16.
// Block: 128(M) x 256(N), 4 waves in 2x2; wave tile 64m x 128n = 4mt x 8nt (acc 128 f32/lane).
// AMODE: 0 f32 A (split hi/lo), 1 LayerNorm-on-load f32 A (split), 2 bf16 A (plain)
// SPLIT: 1 = bf16x2-split (3 MFMAs: hh + lh + hl), 0 = plain bf16
// EPI:   0 relu->f32, 1 f32, 2 relu->bf16, 3 f32 + sum((C-xref)^2) into acc_rec
template <int AMODE, int SPLIT, int EPI>
__global__ __launch_bounds__(256, 2) void k_gemm_mfma(
    const void* __restrict__ Ap, const unsigned short* __restrict__ Bh,
    const unsigned short* __restrict__ Bl,
    const float* __restrict__ bias, void* __restrict__ Cp,
    const int K, const int Nc,
    const float* __restrict__ mu, const float* __restrict__ rsig,
    const float* __restrict__ lng, const float* __restrict__ lnb,
    const float* __restrict__ xref, double* __restrict__ acc_rec)
{
    __shared__ __align__(16) unsigned short BhS[256][40];             // [n][k] pad 8
    __shared__ __align__(16) unsigned short BlS[SPLIT ? 256 : 8][SPLIT ? 40 : 8];
    __shared__ float credsh[4];

    const int t = threadIdx.x;
    const int wave = t >> 6, lane = t & 63;
    const int lg = lane >> 4, lm = lane & 15;
    const int wm = wave >> 1, wn = wave & 1;
    const size_t rowb = (size_t)blockIdx.y * 128 + wm * 64;
    const int nb = blockIdx.x << 8;

    f32x4 acc[4][8];
    #pragma unroll
    for (int mt = 0; mt < 4; ++mt)
        #pragma unroll
        for (int nt = 0; nt < 8; ++nt) acc[mt][nt] = (f32x4){0.f, 0.f, 0.f, 0.f};

    float lnm[4], lnr[4];
    if (AMODE == 1) {
        #pragma unroll
        for (int mt = 0; mt < 4; ++mt) {
            lnm[mt] = mu[rowb + (mt << 4) + lm];
            lnr[mt] = rsig[rowb + (mt << 4) + lm];
        }
    }

    for (int kk = 0; kk < K; kk += 32) {
        // ---- A fragments: per-lane direct global loads ----
        short8 Ah[4], Al[4];
        if (AMODE == 2) {
            #pragma unroll
            for (int mt = 0; mt < 4; ++mt)
                Ah[mt] = *(const short8*)((const unsigned short*)Ap +
                          (rowb + (mt << 4) + lm) * (size_t)K + kk + (lg << 3));
        } else {
            float g[8], bb[8];
            if (AMODE == 1) {
                float4 g0 = *(const float4*)(lng + kk + (lg << 3));
                float4 g1 = *(const float4*)(lng + kk + (lg << 3) + 4);
                float4 b0 = *(const float4*)(lnb + kk + (lg << 3));
                float4 b1 = *(const float4*)(lnb + kk + (lg << 3) + 4);
                g[0]=g0.x; g[1]=g0.y; g[2]=g0.z; g[3]=g0.w; g[4]=g1.x; g[5]=g1.y; g[6]=g1.z; g[7]=g1.w;
                bb[0]=b0.x; bb[1]=b0.y; bb[2]=b0.z; bb[3]=b0.w; bb[4]=b1.x; bb[5]=b1.y; bb[6]=b1.z; bb[7]=b1.w;
            }
            #pragma unroll
            for (int mt = 0; mt < 4; ++mt) {
                const float* ar = (const float*)Ap + (rowb + (mt << 4) + lm) * (size_t)K + kk + (lg << 3);
                float4 a0 = *(const float4*)ar;
                float4 a1 = *(const float4*)(ar + 4);
                float e[8] = {a0.x, a0.y, a0.z, a0.w, a1.x, a1.y, a1.z, a1.w};
                #pragma unroll
                for (int j = 0; j < 8; ++j) {
                    float v = e[j];
                    if (AMODE == 1) v = fmaf((v - lnm[mt]) * lnr[mt], g[j], bb[j]);
                    unsigned short h = f2bf(v);
                    Ah[mt][j] = (short)h;
                    Al[mt][j] = (short)f2bf(v - bf2f(h));
                }
            }
        }
        // ---- stage B tile [256 n][32 k] ----
        __syncthreads();
        {
            const unsigned short* gh = Bh + (size_t)nb * K + kk;
            #pragma unroll
            for (int it = 0; it < 4; ++it) {
                const int idx = (it << 8) + t;
                const int n = idx >> 2, sl = idx & 3;
                *(uint4*)&BhS[n][sl << 3] = *(const uint4*)(gh + (size_t)n * K + (sl << 3));
            }
            if (SPLIT) {
                const unsigned short* gl = Bl + (size_t)nb * K + kk;
                #pragma unroll
                for (int it = 0; it < 4; ++it) {
                    const int idx = (it << 8) + t;
                    const int n = idx >> 2, sl = idx & 3;
                    *(uint4*)&BlS[n][sl << 3] = *(const uint4*)(gl + (size_t)n * K + (sl << 3));
                }
            }
        }
        __syncthreads();
        // ---- MFMA: 4mt x 8nt ----
        #pragma unroll
        for (int nt = 0; nt < 8; ++nt) {
            const int nl = (wn << 7) + (nt << 4) + lm;
            short8 bh = *(const short8*)&BhS[nl][lg << 3];
            if (!SPLIT) {
                #pragma unroll
                for (int mt = 0; mt < 4; ++mt)
                    acc[mt][nt] = mfma_bf16(Ah[mt], bh, acc[mt][nt]);
            } else {
                short8 bl = *(const short8*)&BlS[nl][lg << 3];
                #pragma unroll
                for (int mt = 0; mt < 4; ++mt) {
                    acc[mt][nt] = mfma_bf16(Ah[mt], bh, acc[mt][nt]);
                    acc[mt][nt] = mfma_bf16(Al[mt], bh, acc[mt][nt]);
                    acc[mt][nt] = mfma_bf16(Ah[mt], bl, acc[mt][nt]);
                }
            }
        }
    }

    // ---- epilogue: C[row = rowb+mt*16+lg*4+r][col = nb+wn*128+nt*16+lm] ----
    float lsum = 0.0f;
    #pragma unroll
    for (int nt = 0; nt < 8; ++nt) {
        const int col = nb + (wn << 7) + (nt << 4) + lm;
        const float bs = bias[col];
        #pragma unroll
        for (int mt = 0; mt < 4; ++mt) {
            #pragma unroll
            for (int r = 0; r < 4; ++r) {
                float v = acc[mt][nt][r] + bs;
                if (EPI == 0 || EPI == 2) v = fmaxf(v, 0.0f);
                const size_t row = rowb + (mt << 4) + (lg << 2) + r;
                if (EPI == 2) {
                    ((unsigned short*)Cp)[row * Nc + col] = f2bf(v);
                } else {
                    ((float*)Cp)[row * Nc + col] = v;
                }
                if (EPI == 3) {
                    const float d = v - xref[row * Nc + col];
                    lsum = fmaf(d, d, lsum);
                }
            }
        }
    }
    if (EPI == 3) {
        #pragma unroll
        for (int o = 32; o > 0; o >>= 1) lsum += __shfl_xor(lsum, o);
        if (lane == 0) credsh[wave] = lsum;
        __syncthreads();
        if (t == 0) atomicAdd(acc_rec, (double)((credsh[0] + credsh[1]) + (credsh[2] + credsh[3])));
    }
}

// Fused 4-level residual quantization, MFMA bf16x2-split edition.
// Block = 256 thr = 4 waves; wave owns 32 rows (2 MFMA m-tiles) held entirely in
// registers as hi/lo bf16 A-fragments. Codebook hi/lo async-double-buffer-streamed
// through LDS in 32-code chunks; ONE barrier per chunk.
// Distance accumulators are CHAINED into 2 MFMA accs per m-tile (p0 = hi.hi,
// p1 = lo.hi + hi.lo) instead of 3 separate ones: -32 VGPRs, kills the scratch
// spill that dominated rounds 0-1 (WRITE_SIZE 716 MB vs 33 MB real output).
__global__ __launch_bounds__(256, 2) void k_quant_mfma(
    const float* __restrict__ enc, const float* __restrict__ cb,
    const unsigned short* __restrict__ cbh, const unsigned short* __restrict__ cbl,
    const float* __restrict__ cnorm, unsigned short* __restrict__ qf, float* __restrict__ oidx,
    int* __restrict__ flag, double* __restrict__ acc_commit)
{
    // linear [32][256]-short chunk images, double buffered; value at semantic
    // (row, colbyte c) lives at byte row*512 + (c ^ ((row&7)<<4)).
    __shared__ __align__(128) unsigned short Bh[2][32][256];
    __shared__ __align__(128) unsigned short Bl[2][32][256];
    __shared__ __align__(16) int rowidxsh[128];
    __shared__ float credsh[4];

    const int t = threadIdx.x;
    const int wave = t >> 6, lane = t & 63;
    const int lg = lane >> 4, lm = lane & 15;
    const size_t rowbase = (size_t)blockIdx.x * 128 + wave * 32;

// stage one 32-code chunk (16KB hi + 16KB lo) into buffer b_ via async gload_lds;
// source address pre-swizzled so that swizzled READS return linear data (rule #21).
#define STAGE_CHUNK(b_, gh_, gl_) do {                                          \
    _Pragma("unroll")                                                           \
    for (int i_ = 0; i_ < 4; ++i_) {                                            \
        const int seg_ = (i_ << 2) + wave;                                      \
        const int off_ = (seg_ << 10) + (lane << 4);                            \
        const int src_ = off_ ^ (((off_ >> 9) & 7) << 4);                       \
        gld16((const char*)(gh_) + src_, (char*)&Bh[b_][0][0] + (seg_ << 10));  \
        gld16((const char*)(gl_) + src_, (char*)&Bl[b_][0][0] + (seg_ << 10));  \
    }                                                                           \
} while (0)

    // prologue: prefetch (level 0, chunk 0) into buffer 0 (overlaps A-frag build)
    STAGE_CHUNK(0, cbh, cbl);
    int buf = 0;

    // ---- load enc rows into hi/lo A-fragments (A[m=lane&15][k=lg*8+j], 8 k-steps) ----
    short8 Ah[2][8], Al[2][8];
    #pragma unroll
    for (int mt = 0; mt < 2; ++mt)
        #pragma unroll
        for (int s = 0; s < 8; ++s) {
            const float* er = enc + (rowbase + mt * 16 + lm) * ODIM + s * 32 + lg * 8;
            float4 e0 = *(const float4*)er;
            float4 e1 = *(const float4*)(er + 4);
            float e[8] = {e0.x, e0.y, e0.z, e0.w, e1.x, e1.y, e1.z, e1.w};
            #pragma unroll
            for (int j = 0; j < 8; ++j) {
                unsigned short h = f2bf(e[j]);
                Ah[mt][s][j] = (short)h;
                Al[mt][s][j] = (short)f2bf(e[j] - bf2f(h));
            }
        }

    float commit_local = 0.0f;
    int flg[2][4] = {{0, 0, 0, 0}, {0, 0, 0, 0}};

    for (int l = 0; l < NLEV; ++l) {
        float bestv[2][4], b2v[2][4];
        int besti[2][4];
        #pragma unroll
        for (int mt = 0; mt < 2; ++mt)
            #pragma unroll
            for (int r = 0; r < 4; ++r) { bestv[mt][r] = 3.4e38f; b2v[mt][r] = 3.4e38f; besti[mt][r] = 0; }

        for (int ch = 0; ch < 32; ++ch) {
            // buffer `buf` holds (l,ch) after this barrier (drains prefetch vmcnt);
            // it also guarantees all waves are done reading buf^1 before we refill it.
            __syncthreads();
            {
                const int cc = (l << 5) + ch + 1;          // next chunk, flattened
                if (cc < 128) {
                    const unsigned short* gh = cbh + ((size_t)(cc >> 5) << 18) + ((size_t)(cc & 31) << 13);
                    const unsigned short* gl = cbl + ((size_t)(cc >> 5) << 18) + ((size_t)(cc & 31) << 13);
                    STAGE_CHUNK(buf ^ 1, gh, gl);
                }
            }
            const int cbase = ch << 5;
            const unsigned short* bbh = &Bh[buf][0][0];
            const unsigned short* bbl = &Bl[buf][0][0];
            #pragma unroll
            for (int nt = 0; nt < 2; ++nt) {
                const int rowB = (nt << 4) + lm;
                const int rbase = rowB << 9;               // row byte base
                const int xm = (rowB & 7) << 4;            // XOR swizzle mask
                // chained accumulators: p0 = Ah.bh ; p1 = Al.bh + Ah.bl
                f32x4 p0[2], p1[2];
                #pragma unroll
                for (int mt = 0; mt < 2; ++mt) {
                    p0[mt] = (f32x4){0.f, 0.f, 0.f, 0.f};
                    p1[mt] = (f32x4){0.f, 0.f, 0.f, 0.f};
                }
                #pragma unroll
                for (int s = 0; s < 8; ++s) {
                    const int a = rbase + (((s << 6) + (lg << 4)) ^ xm);
                    short8 bh = *(const short8*)((const char*)bbh + a);
                    short8 bl = *(const short8*)((const char*)bbl + a);
                    p0[0] = mfma_bf16(Ah[0][s], bh, p0[0]);
                    p0[1] = mfma_bf16(Ah[1][s], bh, p0[1]);
                    p1[0] = mfma_bf16(Al[0][s], bh, p1[0]);
                    p1[1] = mfma_bf16(Al[1][s], bh, p1[1]);
                    p1[0] = mfma_bf16(Ah[0][s], bl, p1[0]);
                    p1[1] = mfma_bf16(Ah[1][s], bl, p1[1]);
                }
                const int code = cbase + (nt << 4) + lm;
                const float cn = cnorm[(l << 10) + code];
                #pragma unroll
                for (int mt = 0; mt < 2; ++mt)
                    #pragma unroll
                    for (int r = 0; r < 4; ++r) {
                        const float d = fmaf(-2.0f, p0[mt][r] + p1[mt][r], cn);
                        if (d < bestv[mt][r]) {
                            b2v[mt][r] = bestv[mt][r]; bestv[mt][r] = d; besti[mt][r] = code;
                        } else {
                            b2v[mt][r] = fminf(b2v[mt][r], d);
                        }
                    }
            }
            buf ^= 1;
        }

        // ---- cross-lane argmin over the 16 C-columns (xor butterfly in low 4 lane bits) ----
        #pragma unroll
        for (int mt = 0; mt < 2; ++mt) {
            int iv[4];
            #pragma unroll
            for (int r = 0; r < 4; ++r) {
                float bv = bestv[mt][r], b2 = b2v[mt][r];
                int bi = besti[mt][r];
                #pragma unroll
                for (int off = 1; off < 16; off <<= 1) {
                    float ov = __shfl_xor(bv, off);
                    float o2 = __shfl_xor(b2, off);
                    int   oi = __shfl_xor(bi, off);
                    if (ov < bv)      { b2 = fminf(bv, o2); bv = ov; bi = oi; }
                    else if (ov > bv) { b2 = fminf(b2, ov); }
                    else              { b2 = bv; bi = (oi < bi) ? oi : bi; }
                }
                flg[mt][r] |= (b2 - bv < TAUQ) ? 1 : 0;
                iv[r] = bi;
                if (lm == 0)
                    oidx[(rowbase + (mt << 4) + (lg << 2) + r) * NLEV + l] = (float)bi;
            }
            if (lm == 0)
                *(int4*)&rowidxsh[(wave << 5) + (mt << 4) + (lg << 2)] = make_int4(iv[0], iv[1], iv[2], iv[3]);
        }
        __syncthreads();

        // ---- residual update in registers: r -= cb[best]; commit += r^2; re-split ----
        const size_t lbase = (size_t)l * CBS * ODIM;
        #pragma unroll
        for (int mt = 0; mt < 2; ++mt) {
            const int ci = rowidxsh[(wave << 5) + (mt << 4) + lm];
            const float* cr = cb + lbase + (size_t)ci * ODIM + lg * 8;
            #pragma unroll
            for (int s = 0; s < 8; ++s) {
                float4 c0 = *(const float4*)(cr + (s << 5));
                float4 c1 = *(const float4*)(cr + (s << 5) + 4);
                float c[8] = {c0.x, c0.y, c0.z, c0.w, c1.x, c1.y, c1.z, c1.w};
                #pragma unroll
                for (int j = 0; j < 8; ++j) {
                    float rr = bf2f((unsigned short)Ah[mt][s][j]) + bf2f((unsigned short)Al[mt][s][j]) - c[j];
                    commit_local = fmaf(rr, rr, commit_local);
                    unsigned short h = f2bf(rr);
                    Ah[mt][s][j] = (short)h;
                    Al[mt][s][j] = (short)f2bf(rr - bf2f(h));
                }
            }
        }
    }
#undef STAGE_CHUNK

    // ---- q_final = enc - r_final, stored bf16 for the MFMA decoder ----
    #pragma unroll
    for (int mt = 0; mt < 2; ++mt)
        #pragma unroll
        for (int s = 0; s < 8; ++s) {
            const size_t ro = (rowbase + mt * 16 + lm) * ODIM + s * 32 + lg * 8;
            float4 e0 = *(const float4*)(enc + ro);
            float4 e1 = *(const float4*)(enc + ro + 4);
            float e[8] = {e0.x, e0.y, e0.z, e0.w, e1.x, e1.y, e1.z, e1.w};
            unsigned short q[8];
            #pragma unroll
            for (int j = 0; j < 8; ++j)
                q[j] = f2bf(e[j] - (bf2f((unsigned short)Ah[mt][s][j]) + bf2f((unsigned short)Al[mt][s][j])));
            *(ushort4*)(qf + ro)     = make_ushort4(q[0], q[1], q[2], q[3]);
            *(ushort4*)(qf + ro + 4) = make_ushort4(q[4], q[5], q[6], q[7]);
        }

    if (lm == 0) {
        #pragma unroll
        for (int mt = 0; mt < 2; ++mt)
            #pragma unroll
            for (int r = 0; r < 4; ++r)
                flag[rowbase + (mt << 4) + (lg << 2) + r] = flg[mt][r];
    }

    #pragma unroll
    for (int o = 32; o > 0; o >>= 1) commit_local += __shfl_xor(commit_local, o);
    if (lane == 0) credsh[wave] = commit_local;
    __syncthreads();
    if (t == 0) atomicAdd(acc_commit, (double)((credsh[0] + credsh[1]) + (credsh[2] + credsh[3])));
}

// f64 exact recompute of the index chain for flagged (near-tie) rows.
// Distance scan reads the TRANSPOSED codebook ct[l][k][code]: one coalesced
// float4 per k per lane (codes 4t..4t+3) instead of the stride-1KB 16B walk.
__global__ __launch_bounds__(256) void k_fix(
    const int* __restrict__ flag, const float* __restrict__ x,
    const float* __restrict__ lng, const float* __restrict__ lnb,
    const float* __restrict__ W1, const float* __restrict__ b1,
    const float* __restrict__ W2, const float* __restrict__ b2,
    const float* __restrict__ cb, const float* __restrict__ ct,
    float* __restrict__ oidx)
{
    const int row = blockIdx.x;
    if (!flag[row]) return;
    const int t = threadIdx.x;
    __shared__ double xn[INDIM];
    __shared__ double hs[ODIM];
    __shared__ double r[ODIM];
    __shared__ double rv_[4];
    __shared__ int ri_[4];
    __shared__ int selidx;

    const float* xr = x + (size_t)row * INDIM;
    double xa = (double)xr[t], xb = (double)xr[t + 256], xc = (double)xr[t + 512];
    double s1 = xa + xb + xc;
    double s2 = xa * xa + xb * xb + xc * xc;
    #pragma unroll
    for (int o = 32; o > 0; o >>= 1) { s1 += __shfl_xor(s1, o); s2 += __shfl_xor(s2, o); }
    __shared__ double w1r[4], w2r[4];
    if ((t & 63) == 0) { w1r[t >> 6] = s1; w2r[t >> 6] = s2; }
    __syncthreads();
    double S1 = (w1r[0] + w1r[1]) + (w1r[2] + w1r[3]);
    double S2 = (w2r[0] + w2r[1]) + (w2r[2] + w2r[3]);
    double mu = S1 / (double)INDIM;
    double var = S2 / (double)INDIM - mu * mu;
    double rs = 1.0 / sqrt(var + 1e-5);
    xn[t]       = (xa - mu) * rs * (double)lng[t]       + (double)lnb[t];
    xn[t + 256] = (xb - mu) * rs * (double)lng[t + 256] + (double)lnb[t + 256];
    xn[t + 512] = (xc - mu) * rs * (double)lng[t + 512] + (double)lnb[t + 512];
    __syncthreads();
    {
        double a0 = 0.0, a1 = 0.0, a2 = 0.0, a3 = 0.0;
        for (int k = 0; k < INDIM; k += 4) {
            a0 = fma(xn[k + 0], (double)W1[(size_t)(k + 0) * ODIM + t], a0);
            a1 = fma(xn[k + 1], (double)W1[(size_t)(k + 1) * ODIM + t], a1);
            a2 = fma(xn[k + 2], (double)W1[(size_t)(k + 2) * ODIM + t], a2);
            a3 = fma(xn[k + 3], (double)W1[(size_t)(k + 3) * ODIM + t], a3);
        }
        hs[t] = fmax(((a0 + a1) + (a2 + a3)) + (double)b1[t], 0.0);
    }
    __syncthreads();
    {
        double a0 = 0.0, a1 = 0.0, a2 = 0.0, a3 = 0.0;
        for (int k = 0; k < ODIM; k += 4) {
            a0 = fma(hs[k + 0], (double)W2[(size_t)(k + 0) * ODIM + t], a0);
            a1 = fma(hs[k + 1], (double)W2[(size_t)(k + 1) * ODIM + t], a1);
            a2 = fma(hs[k + 2], (double)W2[(size_t)(k + 2) * ODIM + t], a2);
            a3 = fma(hs[k + 3], (double)W2[(size_t)(k + 3) * ODIM + t], a3);
        }
        r[t] = ((a0 + a1) + (a2 + a3)) + (double)b2[t];
    }
    __syncthreads();

    for (int l = 0; l < NLEV; ++l) {
        const float* ctl = ct + (size_t)l * CBS * ODIM;   // [k][code]
        double d0 = 0.0, d1 = 0.0, d2 = 0.0, d3 = 0.0;
        #pragma unroll 4
        for (int k = 0; k < ODIM; ++k) {
            const double rk = r[k];
            const float4 c4 = *(const float4*)(ctl + ((size_t)k << 10) + (t << 2));
            const double f0 = rk - (double)c4.x;
            const double f1 = rk - (double)c4.y;
            const double f2 = rk - (double)c4.z;
            const double f3 = rk - (double)c4.w;
            d0 = fma(f0, f0, d0); d1 = fma(f1, f1, d1);
            d2 = fma(f2, f2, d2); d3 = fma(f3, f3, d3);
        }
        // per-thread best over codes {4t, 4t+1, 4t+2, 4t+3} (ascending -> lowest-index tie-break)
        double bv = d0; int bi = (t << 2);
        if (d1 < bv) { bv = d1; bi = (t << 2) + 1; }
        if (d2 < bv) { bv = d2; bi = (t << 2) + 2; }
        if (d3 < bv) { bv = d3; bi = (t << 2) + 3; }
        #pragma unroll
        for (int o = 32; o > 0; o >>= 1) {
            double ov = __shfl_xor(bv, o);
            int oi = __shfl_xor(bi, o);
            if (ov < bv || (ov == bv && oi < bi)) { bv = ov; bi = oi; }
        }
        if ((t & 63) == 0) { rv_[t >> 6] = bv; ri_[t >> 6] = bi; }
        __syncthreads();
        if (t == 0) {
            double fv = rv_[0]; int fi = ri_[0];
            #pragma unroll
            for (int w = 1; w < 4; ++w)
                if (rv_[w] < fv || (rv_[w] == fv && ri_[w] < fi)) { fv = rv_[w]; fi = ri_[w]; }
            selidx = fi;
            oidx[(size_t)row * NLEV + l] = (float)fi;
        }
        __syncthreads();
        r[t] = r[t] - (double)cb[(size_t)l * CBS * ODIM + (size_t)selidx * ODIM + t];
        __syncthreads();
    }
}

__global__ void k_fin(const double* __restrict__ acc, float* __restrict__ out) {
    if (threadIdx.x == 0)
        out[0] = (float)(acc[1] / ((double)NROWS * (double)INDIM) +
                         0.25 * (acc[0] / ((double)NROWS * (double)ODIM)));
}

extern "C" void kernel_launch(void* const* d_in, const int* in_sizes, int n_in,
                              void* d_out, int out_size, void* d_ws, size_t ws_size,
                              hipStream_t stream)
{
    const float* x   = (const float*)d_in[0];
    const float* lng = (const float*)d_in[1];
    const float* lnb = (const float*)d_in[2];
    const float* W1  = (const float*)d_in[3];
    const float* b1  = (const float*)d_in[4];
    const float* W2  = (const float*)d_in[5];
    const float* b2  = (const float*)d_in[6];
    const float* Wd1 = (const float*)d_in[7];
    const float* bd1 = (const float*)d_in[8];
    const float* Wd2 = (const float*)d_in[9];
    const float* bd2 = (const float*)d_in[10];
    const float* cbs = (const float*)d_in[11];

    char* ws = (char*)d_ws;
    const size_t MB = 1u << 20;
    const size_t O_ACC  = 0;
    const size_t O_CN   = 1024;
    const size_t O_MU   = O_CN + 16384;
    const size_t O_RS   = O_MU + (size_t)NROWS * 4;
    const size_t O_FLAG = O_RS + (size_t)NROWS * 4;
    const size_t O_ENC  = 1 * MB;                 // 64 MB f32
    const size_t O_QF   = 65 * MB;                // 32 MB bf16
    const size_t O_W1H  = 97 * MB;                // transposed weights, ~2.5 MB total
    const size_t O_W1L  = O_W1H + (size_t)INDIM * ODIM * 2;
    const size_t O_W2H  = O_W1L + (size_t)INDIM * ODIM * 2;
    const size_t O_W2L  = O_W2H + (size_t)ODIM * ODIM * 2;
    const size_t O_WD1  = O_W2L + (size_t)ODIM * ODIM * 2;
    const size_t O_WD2  = O_WD1 + (size_t)ODIM * INDIM * 2;
    const size_t O_CBH  = 100 * MB;               // 2 MB
    const size_t O_CBL  = 102 * MB;               // 2 MB
    const size_t O_H1   = 104 * MB;               // h1 f32 64 MB, later aliased by hd bf16 100 MB
    const size_t O_CT   = O_H1;                   // ct f32 4 MB aliases h1 (free after GEMM2, before decoder)

    double* acc   = (double*)(ws + O_ACC);   // [0]=commit sum, [1]=rec sum
    float* cnorm  = (float*)(ws + O_CN);
    float* mu     = (float*)(ws + O_MU);
    float* rsig   = (float*)(ws + O_RS);
    int*   flag   = (int*)(ws + O_FLAG);
    float* enc    = (float*)(ws + O_ENC);
    unsigned short* qf  = (unsigned short*)(ws + O_QF);
    unsigned short* w1h = (unsigned short*)(ws + O_W1H);
    unsigned short* w1l = (unsigned short*)(ws + O_W1L);
    unsigned short* w2h = (unsigned short*)(ws + O_W2H);
    unsigned short* w2l = (unsigned short*)(ws + O_W2L);
    unsigned short* wd1h = (unsigned short*)(ws + O_WD1);
    unsigned short* wd2h = (unsigned short*)(ws + O_WD2);
    unsigned short* cbh = (unsigned short*)(ws + O_CBH);
    unsigned short* cbl = (unsigned short*)(ws + O_CBL);
    float* h1     = (float*)(ws + O_H1);
    float* ct     = (float*)(ws + O_CT);
    unsigned short* hd = (unsigned short*)(ws + O_H1);

    float* outF  = (float*)d_out;
    float* recon = outF + 1;
    float* oidx  = outF + 1 + (size_t)NROWS * INDIM;

    k_init<<<1, 64, 0, stream>>>(acc);
    k_cnorm<<<NLEV * CBS, 64, 0, stream>>>(cbs, cnorm);
    k_ln<<<NROWS, 256, 0, stream>>>(x, mu, rsig);
    // weight transpose + bf16(x2) conversion
    k_wt<<<ODIM, 256, 0, stream>>>(W1, w1h, w1l, INDIM, ODIM, 1);
    k_wt<<<ODIM, 256, 0, stream>>>(W2, w2h, w2l, ODIM, ODIM, 1);
    k_wt<<<INDIM, 256, 0, stream>>>(Wd1, wd1h, nullptr, ODIM, INDIM, 0);
    k_wt<<<INDIM, 256, 0, stream>>>(Wd2, wd2h, nullptr, INDIM, INDIM, 0);
    k_split<<<(NLEV * CBS * ODIM) / 1024, 256, 0, stream>>>(cbs, cbh, cbl);
    // encoder: LN(x)@W1 relu -> h1;  h1@W2 -> enc   (bf16x2-split MFMA)
    k_gemm_mfma<1, 1, 0><<<dim3(1, NROWS / 128), 256, 0, stream>>>(
        x, w1h, w1l, b1, h1, INDIM, ODIM, mu, rsig, lng, lnb, nullptr, nullptr);
    k_gemm_mfma<0, 1, 1><<<dim3(1, NROWS / 128), 256, 0, stream>>>(
        h1, w2h, w2l, b2, enc, ODIM, ODIM, nullptr, nullptr, nullptr, nullptr, nullptr, nullptr);
    // codebook transpose for k_fix (h1 is dead from here on; hd overwrites ct only after k_fix)
    k_cbt<<<dim3(32, 8, 4), 256, 0, stream>>>(cbs, ct);
    // residual quantization: MFMA bf16x2-split + near-tie flags, qf out bf16
    k_quant_mfma<<<NROWS / 128, 256, 0, stream>>>(enc, cbs, cbh, cbl, cnorm, qf, oidx, flag, acc);
    // f64 exact index fix for flagged rows (coalesced transposed-codebook scan)
    k_fix<<<NROWS, 256, 0, stream>>>(flag, x, lng, lnb, W1, b1, W2, b2, cbs, ct, oidx);
    // decoder: qf@Wd1 relu -> hd (bf16);  hd@Wd2 -> recon + rec_loss   (plain bf16 MFMA)
    k_gemm_mfma<2, 0, 2><<<dim3(INDIM / 256, NROWS / 128), 256, 0, stream>>>(
        qf, wd1h, nullptr, bd1, hd, ODIM, INDIM, nullptr, nullptr, nullptr, nullptr, nullptr, nullptr);
    k_gemm_mfma<2, 0, 3><<<dim3(INDIM / 256, NROWS / 128), 256, 0, stream>>>(
        hd, wd2h, nullptr, bd2, recon, INDIM, INDIM, nullptr, nullptr, nullptr, nullptr, x, acc + 1);
    k_fin<<<1, 64, 0, stream>>>(acc, outF);
}